// Round 8
// baseline (880.744 us; speedup 1.0000x reference)
//
#include <hip/hip_runtime.h>
#include <math.h>

#define BGR 256        // graphs
#define NPG0 400       // nodes per graph
#define NN (BGR*NPG0)  // 102400 nodes
#define NE (NN*16)     // 1638400 edges
#define EPG (NPG0*16)  // 6400 edges per graph (contiguous)
#define HD 128
#define AST 416        // adjacency / XT column count (13*32, zero-padded)
#define KSA 13         // agg k-steps
#define MSTR 136       // LDS tile row stride (shorts)

typedef __attribute__((ext_vector_type(8))) short short8;
typedef __attribute__((ext_vector_type(4))) float floatx4;

__device__ __forceinline__ unsigned short f2b(float f) {
    unsigned int u = __builtin_bit_cast(unsigned int, f);
    unsigned int r = (u + 0x7fffu + ((u >> 16) & 1u)) >> 16;
    return (unsigned short)r;
}
__device__ __forceinline__ unsigned int pk2(float a, float b) {
    return (unsigned int)f2b(a) | ((unsigned int)f2b(b) << 16);
}
__device__ __forceinline__ float b2f(unsigned short h) {
    return __builtin_bit_cast(float, (unsigned int)h << 16);
}
__device__ __forceinline__ float b2f_lo(unsigned int u) { return __builtin_bit_cast(float, u << 16); }
__device__ __forceinline__ float b2f_hi(unsigned int u) { return __builtin_bit_cast(float, u & 0xffff0000u); }
__device__ __forceinline__ unsigned short bfint(unsigned int v) {
    return (unsigned short)(__builtin_bit_cast(unsigned int, (float)v) >> 16);   // exact for v<256
}

// ---------------- adjacency build: u8 global atomics (stride AST, memset-zeroed)
__global__ void k_abuild(const int* __restrict__ src, const int* __restrict__ dst,
                         unsigned int* __restrict__ A8) {
    int e = blockIdx.x * 256 + threadIdx.x;
    if (e >= NE) return;
    int g = e / EPG;                       // edges grouped by graph
    int sl = src[e] - g * NPG0;
    int dl = dst[e] - g * NPG0;
    long idx = ((long)g * NPG0 + dl) * AST + sl;
    atomicAdd(&A8[idx >> 2], 1u << ((idx & 3) * 8));
}

// ---------------- u8 -> bf16 adjacency + rowsum -> rliv, alive=1 (one wave per row)
__global__ __launch_bounds__(256) void k_acvt(const unsigned char* __restrict__ A8,
    unsigned short* __restrict__ Abf, float* __restrict__ alive, float* __restrict__ rliv) {
    int wid = threadIdx.x >> 6, lane = threadIdx.x & 63;
    long row = (long)blockIdx.x * 4 + wid;
    const unsigned int* in = (const unsigned int*)(A8 + row * AST);
    unsigned int* outp = (unsigned int*)(Abf + row * AST);
    unsigned int ssum = 0;
    for (int i = lane; i < AST / 4; i += 64) {
        unsigned int u = in[i];
        uint2 o;
        o.x = (unsigned)bfint(u & 0xffu) | ((unsigned)bfint((u >> 8) & 0xffu) << 16);
        o.y = (unsigned)bfint((u >> 16) & 0xffu) | ((unsigned)bfint(u >> 24) << 16);
        *(uint2*)&outp[2 * i] = o;
        unsigned int t1 = (u & 0x00FF00FFu) + ((u >> 8) & 0x00FF00FFu);
        ssum += (t1 & 0xffffu) + (t1 >> 16);
    }
#pragma unroll
    for (int m2 = 1; m2 < 64; m2 <<= 1) ssum += __shfl_xor(ssum, m2);
    if (lane == 0) {
        rliv[row] = 1.0f / fmaxf((float)ssum, 1.0f);
        alive[row] = 1.0f;
    }
}

// ---------------- W -> bf16, transposed (W^T row-major)
__global__ void k_wcvt(const float* __restrict__ c1_wr, const float* __restrict__ c1_ws,
                       const float* __restrict__ cs_wr, const float* __restrict__ cs_ws,
                       unsigned short* __restrict__ bt) {
    int m = blockIdx.y;
    int idx = blockIdx.x * 256 + threadIdx.x;
    const float* W = (m == 0) ? c1_wr : (m == 1) ? c1_ws
                   : (m < 6) ? (cs_wr + (m - 2) * HD * HD) : (cs_ws + (m - 6) * HD * HD);
    int n = idx >> 7, k = idx & 127;
    bt[m * HD * HD + idx] = f2b(W[k * HD + n]);
}

// ---------------- x_in fp32 [node][128] -> XT0 bf16 [g][f][AST] (pads left garbage-OK)
__global__ __launch_bounds__(256) void k_xpose(const float* __restrict__ x,
                                               unsigned short* __restrict__ XT) {
    __shared__ unsigned short sT[128 * 104];   // [f][node] tile (100 nodes, stride 104)
    int b = blockIdx.x;
    int g = b >> 2, qq = b & 3;
    int n0 = qq * 100;
    long gn = (long)g * NPG0;
    int t = threadIdx.x;
    for (int idx = t; idx < 100 * 32; idx += 256) {
        int n = idx >> 5, c = idx & 31;
        float4 v = ((const float4*)x)[(gn + n0 + n) * 32 + c];
        sT[(c * 4 + 0) * 104 + n] = f2b(v.x);
        sT[(c * 4 + 1) * 104 + n] = f2b(v.y);
        sT[(c * 4 + 2) * 104 + n] = f2b(v.z);
        sT[(c * 4 + 3) * 104 + n] = f2b(v.w);
    }
    __syncthreads();
    for (int idx = t; idx < 128 * 50; idx += 256) {
        int f = idx / 50, np = idx % 50;
        unsigned int u = (unsigned)sT[f * 104 + 2 * np] | ((unsigned)sT[f * 104 + 2 * np + 1] << 16);
        ((unsigned int*)XT)[((long)g * HD + f) * (AST / 2) + (n0 >> 1) + np] = u;
    }
}

// ---------------- fused layer: 4 blocks/graph (node-quarters), 256 thr = 4 waves
// phase A: stage x normal-tile into sX from XT rows (LDS scatter)
// phase B: preload agg A-frags (XT rows, global b128)
// phase C: meanT = XT . A^T (B = bf16 adjacency rows) -> sM normal layout, * rliv
// phase D: OUT^T = WrT.meanT + WsT.xT + b ; relu, alive-gate, store XTout, fused readout
__global__ __launch_bounds__(256, 2) void k_layer3(
    const unsigned short* __restrict__ XTin, unsigned short* __restrict__ XTout,
    const unsigned short* __restrict__ Abf,
    const float* __restrict__ alive, const float* __restrict__ rliv,
    const unsigned short* __restrict__ wr_bt, const unsigned short* __restrict__ ws_bt,
    const float* __restrict__ bias, float* __restrict__ hcat, int layer)
{
    __shared__ unsigned short sM[112 * MSTR];
    __shared__ unsigned short sX[112 * MSTR];
    int t = threadIdx.x;
    int g = blockIdx.x >> 2, q = blockIdx.x & 3;
    int ntB = q ? 6 * q + 1 : 0;
    int ntE = 6 * q + 7;                 // tiles: 7,6,6,6
    int nrows = (ntE - ntB) * 16;
    int rows0 = ntB * 16;
    long gx = (long)g * HD;
    long gn = (long)g * NPG0;

    // ---- phase A: x normal tile (sX[node][f]) from XT rows
    {
        int npair = nrows >> 1;
        const unsigned int* XTu = (const unsigned int*)XTin;
        for (int idx = t; idx < 128 * 64; idx += 256) {
            int f = idx >> 6, np = idx & 63;
            if (np < npair) {
                unsigned int u = XTu[(gx + f) * (AST / 2) + (rows0 >> 1) + np];
                sX[(2 * np) * MSTR + f] = (unsigned short)(u & 0xffffu);
                sX[(2 * np + 1) * MSTR + f] = (unsigned short)(u >> 16);
            }
        }
    }

    int lane = t & 63, mp = t >> 6;
    int quad = lane >> 4, l15 = lane & 15;

    // ---- phase B: preload agg A-frags (wave mp owns features 32mp..32mp+31)
    short8 Afr[2][KSA];
#pragma unroll
    for (int mt = 0; mt < 2; ++mt)
#pragma unroll
        for (int k = 0; k < KSA; ++k)
            Afr[mt][k] = *(const short8*)&XTin[(gx + 32 * mp + 16 * mt + l15) * AST + k * 32 + quad * 8];

    // ---- phase C: agg GEMM, mean -> sM (normal layout)
    for (int nt = ntB; nt < ntE; ++nt) {
        const unsigned short* Ar = Abf + (gn + nt * 16 + l15) * AST;
        floatx4 acc0 = {0.f, 0.f, 0.f, 0.f};
        floatx4 acc1 = {0.f, 0.f, 0.f, 0.f};
#pragma unroll
        for (int k = 0; k < KSA; ++k) {
            short8 Bf = *(const short8*)&Ar[k * 32 + quad * 8];
            acc0 = __builtin_amdgcn_mfma_f32_16x16x32_bf16(Afr[0][k], Bf, acc0, 0, 0, 0);
            acc1 = __builtin_amdgcn_mfma_f32_16x16x32_bf16(Afr[1][k], Bf, acc1, 0, 0, 0);
        }
        int lo = (nt - ntB) * 16 + l15;
        float rl = rliv[gn + nt * 16 + l15];
        unsigned short* mrow = &sM[lo * MSTR + 32 * mp + quad * 4];
        uint2 w0, w1;
        w0.x = pk2(acc0[0] * rl, acc0[1] * rl); w0.y = pk2(acc0[2] * rl, acc0[3] * rl);
        w1.x = pk2(acc1[0] * rl, acc1[1] * rl); w1.y = pk2(acc1[2] * rl, acc1[3] * rl);
        *(uint2*)mrow = w0;
        *(uint2*)(mrow + 16) = w1;
    }
    __syncthreads();

    // ---- phase D: OUT^T = WrT.meanT + WsT.xT + b
    short8 Wr8[2][4], Ws8[2][4];
#pragma unroll
    for (int mt = 0; mt < 2; ++mt) {
        int j = 32 * mp + 16 * mt + l15;
#pragma unroll
        for (int k = 0; k < 4; ++k) {
            Wr8[mt][k] = *(const short8*)&wr_bt[j * HD + k * 32 + quad * 8];
            Ws8[mt][k] = *(const short8*)&ws_bt[j * HD + k * 32 + quad * 8];
        }
    }
    float4 b40 = *(const float4*)&bias[32 * mp + quad * 4];
    float4 b41 = *(const float4*)&bias[32 * mp + 16 + quad * 4];
    float ps0[4] = {0, 0, 0, 0}, ps1[4] = {0, 0, 0, 0};

    for (int nt = ntB; nt < ntE; ++nt) {
        int o = nt * 16 + l15;
        int lo = (nt - ntB) * 16 + l15;
        floatx4 a0 = {b40.x, b40.y, b40.z, b40.w};
        floatx4 a1 = {b41.x, b41.y, b41.z, b41.w};
#pragma unroll
        for (int k = 0; k < 4; ++k) {
            short8 B0 = *(const short8*)&sM[lo * MSTR + k * 32 + quad * 8];
            a0 = __builtin_amdgcn_mfma_f32_16x16x32_bf16(Wr8[0][k], B0, a0, 0, 0, 0);
            a1 = __builtin_amdgcn_mfma_f32_16x16x32_bf16(Wr8[1][k], B0, a1, 0, 0, 0);
        }
#pragma unroll
        for (int k = 0; k < 4; ++k) {
            short8 B1 = *(const short8*)&sX[lo * MSTR + k * 32 + quad * 8];
            a0 = __builtin_amdgcn_mfma_f32_16x16x32_bf16(Ws8[0][k], B1, a0, 0, 0, 0);
            a1 = __builtin_amdgcn_mfma_f32_16x16x32_bf16(Ws8[1][k], B1, a1, 0, 0, 0);
        }
        bool liv = alive[gn + o] != 0.0f;
#pragma unroll
        for (int rr = 0; rr < 4; ++rr) {
            float v0 = fmaxf(a0[rr], 0.0f);
            float v1 = fmaxf(a1[rr], 0.0f);
            if (liv) { ps0[rr] += v0; ps1[rr] += v1; }
            else { v0 = 0.0f; v1 = 0.0f; }
            int j0 = 32 * mp + quad * 4 + rr;
            XTout[(gx + j0) * AST + o] = f2b(v0);
            XTout[(gx + j0 + 16) * AST + o] = f2b(v1);
        }
    }
    // fused readout: reduce over node lanes (l15), atomic into hcat
#pragma unroll
    for (int rr = 0; rr < 4; ++rr) {
        float v = ps0[rr];
        v += __shfl_xor(v, 1); v += __shfl_xor(v, 2); v += __shfl_xor(v, 4); v += __shfl_xor(v, 8);
        float u = ps1[rr];
        u += __shfl_xor(u, 1); u += __shfl_xor(u, 2); u += __shfl_xor(u, 4); u += __shfl_xor(u, 8);
        if (l15 == 0) {
            atomicAdd(&hcat[g * (5 * HD) + layer * HD + 32 * mp + quad * 4 + rr], v);
            atomicAdd(&hcat[g * (5 * HD) + layer * HD + 32 * mp + 16 + quad * 4 + rr], u);
        }
    }
}

// ---------------- fused pool: dots + score + top-K + tanh-scale (in-place on XT) + rliv
__global__ __launch_bounds__(256) void k_topk(unsigned short* __restrict__ XT,
    const unsigned short* __restrict__ Abf,
    const float* __restrict__ wr, const float* __restrict__ ws, const float* __restrict__ pb,
    float* __restrict__ alive, float* __restrict__ rliv, int K)
{
    __shared__ float str[NPG0];
    __shared__ float stsb[NPG0];
    __shared__ float skf[NPG0];
    __shared__ float s[512];
    __shared__ float sc[NPG0];
    __shared__ float smult[NPG0];
    __shared__ unsigned char keep[NPG0];
    __shared__ int cnt_gt;
    int g = blockIdx.x, t = threadIdx.x;
    long gn = (long)g * NPG0;
    long gx = (long)g * HD;

    // phase 0: dots (coalesced across threads per feature step)
    for (int n = t; n < NPG0; n += 256) {
        float a = 0.0f, c = 0.0f;
        for (int f = 0; f < HD; ++f) {
            float xv = b2f(XT[(gx + f) * AST + n]);
            a = fmaf(xv, wr[f], a);
            c = fmaf(xv, ws[f], c);
        }
        str[n] = a;
        stsb[n] = c + pb[0];
    }
    if (t == 0) cnt_gt = 0;
    __syncthreads();

    // phase 1: score = (A . tr) * rliv + tsb
    for (int n = t; n < 512; n += 256) {
        float v = -INFINITY;
        if (n < NPG0 && alive[gn + n] != 0.0f) {
            const unsigned int* Ar = (const unsigned int*)(Abf + (gn + n) * AST);
            const float2* tp = (const float2*)str;
            float acc = 0.0f;
            for (int w = 0; w < NPG0 / 2; ++w) {
                unsigned int a = Ar[w];
                float2 tv = tp[w];
                acc = fmaf(b2f_lo(a), tv.x, acc);
                acc = fmaf(b2f_hi(a), tv.y, acc);
            }
            v = acc * rliv[gn + n] + stsb[n];
        }
        s[n] = v;
        if (n < NPG0) sc[n] = v;
    }
    __syncthreads();

    // phase 2: bitonic sort for K-th largest
    for (int ksz = 2; ksz <= 512; ksz <<= 1) {
        for (int jsz = ksz >> 1; jsz >= 1; jsz >>= 1) {
            for (int i = t; i < 512; i += 256) {
                int ixj = i ^ jsz;
                if (ixj > i) {
                    float a = s[i], c = s[ixj];
                    bool up = ((i & ksz) == 0);
                    if ((a > c) == up) { s[i] = c; s[ixj] = a; }
                }
            }
            __syncthreads();
        }
    }
    float thr = s[512 - K];
    for (int n = t; n < NPG0; n += 256)
        if (sc[n] > thr) atomicAdd(&cnt_gt, 1);
    __syncthreads();
    if (t == 0) {   // tie-break: lowest index (matches lax.top_k)
        int m = K - cnt_gt, tk = 0;
        for (int n = 0; n < NPG0; n++) {
            bool kp = sc[n] > thr;
            if (!kp && sc[n] == thr && tk < m) { kp = true; tk++; }
            keep[n] = kp ? 1 : 0;
        }
    }
    __syncthreads();
    for (int n = t; n < NPG0; n += 256) {
        bool kp = keep[n] != 0;
        smult[n] = kp ? tanhf(sc[n]) : 0.0f;
        alive[gn + n] = kp ? 1.0f : 0.0f;
        skf[n] = kp ? 1.0f : 0.0f;
    }
    __syncthreads();
    // phase 3: rliv update (alive in-degree = A . keep)
    for (int n = t; n < NPG0; n += 256) {
        const unsigned int* Ar = (const unsigned int*)(Abf + (gn + n) * AST);
        const float2* kp2 = (const float2*)skf;
        float acc = 0.0f;
        for (int w = 0; w < NPG0 / 2; ++w) {
            unsigned int a = Ar[w];
            float2 kv = kp2[w];
            acc = fmaf(b2f_lo(a), kv.x, acc);
            acc = fmaf(b2f_hi(a), kv.y, acc);
        }
        rliv[gn + n] = 1.0f / fmaxf(acc, 1.0f);
    }
    // phase 4: scale XT columns in place (kept *= tanh, dropped -> 0)
    for (int idx = t; idx < HD * (NPG0 / 2); idx += 256) {
        int f = idx / (NPG0 / 2), np = idx % (NPG0 / 2);
        unsigned int* p = &((unsigned int*)XT)[(gx + f) * (AST / 2) + np];
        unsigned int u = *p;
        *p = pk2(b2f_lo(u) * smult[2 * np], b2f_hi(u) * smult[2 * np + 1]);
    }
}

// ---------------- final MLP + log_softmax (hcat holds SUMS; divide here)
__global__ __launch_bounds__(256) void k_mlp(const float* __restrict__ h, const float* __restrict__ w1,
    const float* __restrict__ b1, const float* __restrict__ w2,
    const float* __restrict__ b2, float* __restrict__ out) {
    __shared__ float shg[5 * HD];
    __shared__ float prt[256];
    __shared__ float h1[HD];
    __shared__ float red[HD];
    __shared__ float lg[2];
    const float inv[5] = {1.0f/400.0f, 1.0f/400.0f, 1.0f/320.0f, 1.0f/320.0f, 1.0f/256.0f};
    int g = blockIdx.x, t = threadIdx.x;
    for (int k = t; k < 5 * HD; k += 256) shg[k] = h[g * (5 * HD) + k] * inv[k >> 7];
    __syncthreads();
    int j = t & 127, half = t >> 7;
    float acc = half ? 0.0f : b1[j];
    for (int k = half * 320; k < half * 320 + 320; ++k)
        acc = fmaf(shg[k], w1[k * HD + j], acc);
    prt[t] = acc;
    __syncthreads();
    if (t < HD) h1[t] = fmaxf(prt[t] + prt[t + 128], 0.0f);
    __syncthreads();
    for (int c = 0; c < 2; c++) {
        if (t < HD) red[t] = h1[t] * w2[t * 2 + c];
        __syncthreads();
        for (int st = 64; st > 0; st >>= 1) {
            if (t < st) red[t] += red[t + st];
            __syncthreads();
        }
        if (t == 0) lg[c] = red[0] + b2[c];
        __syncthreads();
    }
    if (t == 0) {
        float l0 = lg[0], l1 = lg[1];
        float m = fmaxf(l0, l1);
        float lse = m + logf(expf(l0 - m) + expf(l1 - m));
        out[g * 2 + 0] = l0 - lse;
        out[g * 2 + 1] = l1 - lse;
    }
}

extern "C" void kernel_launch(void* const* d_in, const int* in_sizes, int n_in,
                              void* d_out, int out_size, void* d_ws, size_t ws_size,
                              hipStream_t stream) {
    const float* x_in   = (const float*)d_in[0];
    const int*   eidx   = (const int*)d_in[1];
    const int*   e_src  = eidx;
    const int*   e_dst  = eidx + NE;
    const float* c1_wr  = (const float*)d_in[3];
    const float* c1_ws  = (const float*)d_in[4];
    const float* c1_b   = (const float*)d_in[5];
    const float* cs_wr  = (const float*)d_in[6];
    const float* cs_ws  = (const float*)d_in[7];
    const float* cs_b   = (const float*)d_in[8];
    const float* p_wr   = (const float*)d_in[9];
    const float* p_ws   = (const float*)d_in[10];
    const float* p_b    = (const float*)d_in[11];
    const float* l1_w   = (const float*)d_in[12];
    const float* l1_b   = (const float*)d_in[13];
    const float* l2_w   = (const float*)d_in[14];
    const float* l2_b   = (const float*)d_in[15];
    float* out = (float*)d_out;

    char* ws = (char*)d_ws;
    size_t off = 0;
    float* alive = (float*)(ws + off);                 off += (size_t)NN * 4;
    float* rliv  = (float*)(ws + off);                 off += (size_t)NN * 4;
    float* hcat  = (float*)(ws + off);                 off += (size_t)BGR * 5 * HD * 4;
    unsigned short* wbt = (unsigned short*)(ws + off); off += (size_t)10 * HD * HD * 2;
    unsigned short* Abf = (unsigned short*)(ws + off); off += (size_t)NN * AST * 2;
    // XT region (2 buffers, 27.3 MB each); A8 (42.6 MB) aliases its head (dead after k_acvt)
    unsigned short* XT0 = (unsigned short*)(ws + off); off += (size_t)BGR * HD * AST * 2;
    unsigned short* XT1 = (unsigned short*)(ws + off); off += (size_t)BGR * HD * AST * 2;
    unsigned char* A8 = (unsigned char*)XT0;

    hipMemsetAsync(A8, 0, (size_t)NN * AST, stream);
    hipMemsetAsync(hcat, 0, (size_t)BGR * 5 * HD * 4, stream);
    k_abuild<<<NE / 256, 256, 0, stream>>>(e_src, e_dst, (unsigned int*)A8);
    k_acvt<<<NN / 4, 256, 0, stream>>>(A8, Abf, alive, rliv);
    k_wcvt<<<dim3(64, 10), 256, 0, stream>>>(c1_wr, c1_ws, cs_wr, cs_ws, wbt);
    k_xpose<<<BGR * 4, 256, 0, stream>>>(x_in, XT0);   // overwrites A8 (dead)

    unsigned short* bt_wr[5] = { wbt + 0 * HD * HD, wbt + 2 * HD * HD, wbt + 3 * HD * HD, wbt + 4 * HD * HD, wbt + 5 * HD * HD };
    unsigned short* bt_ws[5] = { wbt + 1 * HD * HD, wbt + 6 * HD * HD, wbt + 7 * HD * HD, wbt + 8 * HD * HD, wbt + 9 * HD * HD };

    // conv1: XT0 -> XT1
    k_layer3<<<BGR * 4, 256, 0, stream>>>(XT0, XT1, Abf, alive, rliv,
                                          bt_wr[0], bt_ws[0], c1_b, hcat, 0);
    // convs[0]: XT1 -> XT0
    k_layer3<<<BGR * 4, 256, 0, stream>>>(XT1, XT0, Abf, alive, rliv,
                                          bt_wr[1], bt_ws[1], cs_b + 0 * HD, hcat, 1);
    // pool 0 (K=320) on XT0 (dots + topk + in-place scale)
    k_topk<<<BGR, 256, 0, stream>>>(XT0, Abf, p_wr + 0 * HD, p_ws + 0 * HD, p_b + 0,
                                    alive, rliv, 320);
    // convs[1]: XT0 -> XT1
    k_layer3<<<BGR * 4, 256, 0, stream>>>(XT0, XT1, Abf, alive, rliv,
                                          bt_wr[2], bt_ws[2], cs_b + 1 * HD, hcat, 2);
    // convs[2]: XT1 -> XT0
    k_layer3<<<BGR * 4, 256, 0, stream>>>(XT1, XT0, Abf, alive, rliv,
                                          bt_wr[3], bt_ws[3], cs_b + 2 * HD, hcat, 3);
    // pool 1 (K=256) on XT0
    k_topk<<<BGR, 256, 0, stream>>>(XT0, Abf, p_wr + 1 * HD, p_ws + 1 * HD, p_b + 1,
                                    alive, rliv, 256);
    // convs[3]: XT0 -> XT1
    k_layer3<<<BGR * 4, 256, 0, stream>>>(XT0, XT1, Abf, alive, rliv,
                                          bt_wr[4], bt_ws[4], cs_b + 3 * HD, hcat, 4);
    // MLP head
    k_mlp<<<BGR, 256, 0, stream>>>(hcat, l1_w, l1_b, l2_w, l2_b, out);
}

// Round 9
// 800.589 us; speedup vs baseline: 1.1001x; 1.1001x over previous
//
#include <hip/hip_runtime.h>
#include <math.h>

#define BGR 256        // graphs
#define NPG0 400       // nodes per graph
#define NN (BGR*NPG0)  // 102400 nodes
#define NE (NN*16)     // 1638400 edges
#define EPG (NPG0*16)  // 6400 edges per graph (contiguous)
#define HD 128
#define AST 416        // adjacency / XT column count (13*32, zero-padded)
#define KSA 13         // agg k-steps
#define MSTR 136       // LDS tile row stride (shorts)

typedef __attribute__((ext_vector_type(8))) short short8;
typedef __attribute__((ext_vector_type(4))) float floatx4;

__device__ __forceinline__ unsigned short f2b(float f) {
    unsigned int u = __builtin_bit_cast(unsigned int, f);
    unsigned int r = (u + 0x7fffu + ((u >> 16) & 1u)) >> 16;
    return (unsigned short)r;
}
__device__ __forceinline__ unsigned int pk2(float a, float b) {
    return (unsigned int)f2b(a) | ((unsigned int)f2b(b) << 16);
}
__device__ __forceinline__ float b2f(unsigned short h) {
    return __builtin_bit_cast(float, (unsigned int)h << 16);
}
__device__ __forceinline__ float b2f_lo(unsigned int u) { return __builtin_bit_cast(float, u << 16); }
__device__ __forceinline__ float b2f_hi(unsigned int u) { return __builtin_bit_cast(float, u & 0xffff0000u); }
__device__ __forceinline__ unsigned short bfint(unsigned int v) {
    return (unsigned short)(__builtin_bit_cast(unsigned int, (float)v) >> 16);   // exact for v<256
}

// ---------------- adjacency build: u8 global atomics (stride AST, memset-zeroed)
__global__ void k_abuild(const int* __restrict__ src, const int* __restrict__ dst,
                         unsigned int* __restrict__ A8) {
    int e = blockIdx.x * 256 + threadIdx.x;
    if (e >= NE) return;
    int g = e / EPG;                       // edges grouped by graph
    int sl = src[e] - g * NPG0;
    int dl = dst[e] - g * NPG0;
    long idx = ((long)g * NPG0 + dl) * AST + sl;
    atomicAdd(&A8[idx >> 2], 1u << ((idx & 3) * 8));
}

// ---------------- u8 -> bf16 adjacency + rowsum -> rliv, alive=1 (one wave per row)
__global__ __launch_bounds__(256) void k_acvt(const unsigned char* __restrict__ A8,
    unsigned short* __restrict__ Abf, float* __restrict__ alive, float* __restrict__ rliv) {
    int wid = threadIdx.x >> 6, lane = threadIdx.x & 63;
    long row = (long)blockIdx.x * 4 + wid;
    const unsigned int* in = (const unsigned int*)(A8 + row * AST);
    unsigned int* outp = (unsigned int*)(Abf + row * AST);
    unsigned int ssum = 0;
    for (int i = lane; i < AST / 4; i += 64) {
        unsigned int u = in[i];
        uint2 o;
        o.x = (unsigned)bfint(u & 0xffu) | ((unsigned)bfint((u >> 8) & 0xffu) << 16);
        o.y = (unsigned)bfint((u >> 16) & 0xffu) | ((unsigned)bfint(u >> 24) << 16);
        *(uint2*)&outp[2 * i] = o;
        unsigned int t1 = (u & 0x00FF00FFu) + ((u >> 8) & 0x00FF00FFu);
        ssum += (t1 & 0xffffu) + (t1 >> 16);
    }
#pragma unroll
    for (int m2 = 1; m2 < 64; m2 <<= 1) ssum += __shfl_xor(ssum, m2);
    if (lane == 0) {
        rliv[row] = 1.0f / fmaxf((float)ssum, 1.0f);
        alive[row] = 1.0f;
    }
}

// ---------------- W -> bf16, transposed (W^T row-major)
__global__ void k_wcvt(const float* __restrict__ c1_wr, const float* __restrict__ c1_ws,
                       const float* __restrict__ cs_wr, const float* __restrict__ cs_ws,
                       unsigned short* __restrict__ bt) {
    int m = blockIdx.y;
    int idx = blockIdx.x * 256 + threadIdx.x;
    const float* W = (m == 0) ? c1_wr : (m == 1) ? c1_ws
                   : (m < 6) ? (cs_wr + (m - 2) * HD * HD) : (cs_ws + (m - 6) * HD * HD);
    int n = idx >> 7, k = idx & 127;
    bt[m * HD * HD + idx] = f2b(W[k * HD + n]);
}

// ---------------- x_in fp32 [node][128] -> XT0 bf16 [g][f][AST]
__global__ __launch_bounds__(256) void k_xpose(const float* __restrict__ x,
                                               unsigned short* __restrict__ XT) {
    __shared__ unsigned short sT[128 * 104];
    int b = blockIdx.x;
    int g = b >> 2, qq = b & 3;
    int n0 = qq * 100;
    long gn = (long)g * NPG0;
    int t = threadIdx.x;
    for (int idx = t; idx < 100 * 32; idx += 256) {
        int n = idx >> 5, c = idx & 31;
        float4 v = ((const float4*)x)[(gn + n0 + n) * 32 + c];
        sT[(c * 4 + 0) * 104 + n] = f2b(v.x);
        sT[(c * 4 + 1) * 104 + n] = f2b(v.y);
        sT[(c * 4 + 2) * 104 + n] = f2b(v.z);
        sT[(c * 4 + 3) * 104 + n] = f2b(v.w);
    }
    __syncthreads();
    for (int idx = t; idx < 128 * 50; idx += 256) {
        int f = idx / 50, np = idx % 50;
        unsigned int u = (unsigned)sT[f * 104 + 2 * np] | ((unsigned)sT[f * 104 + 2 * np + 1] << 16);
        ((unsigned int*)XT)[((long)g * HD + f) * (AST / 2) + (n0 >> 1) + np] = u;
    }
}

// ---------------- fused layer: 4 blocks/graph; XCD-swizzled so same-graph blocks share L2
// optional epilogue: pool dots tr = x.wr, ts = x.ws written to trg/tsg
__global__ __launch_bounds__(256, 2) void k_layer4(
    const unsigned short* __restrict__ XTin, unsigned short* __restrict__ XTout,
    const unsigned short* __restrict__ Abf,
    const float* __restrict__ alive, const float* __restrict__ rliv,
    const unsigned short* __restrict__ wr_bt, const unsigned short* __restrict__ ws_bt,
    const float* __restrict__ bias, float* __restrict__ hcat, int layer,
    const float* __restrict__ pwr, const float* __restrict__ pws,
    float* __restrict__ trg, float* __restrict__ tsg)
{
    __shared__ unsigned short sM[112 * MSTR];
    __shared__ unsigned short sX[112 * MSTR];
    __shared__ float sTr[4 * 112];
    __shared__ float sTs[4 * 112];
    int t = threadIdx.x;
    int g = blockIdx.x & 255, q = blockIdx.x >> 8;   // same-graph blocks: b%8 == g%8 (XCD share)
    int ntB = q ? 6 * q + 1 : 0;
    int ntE = 6 * q + 7;                 // tiles: 7,6,6,6
    int nrows = (ntE - ntB) * 16;
    int rows0 = ntB * 16;
    long gx = (long)g * HD;
    long gn = (long)g * NPG0;

    // ---- phase A: x normal tile (sX[node][f]) from XT rows
    {
        int npair = nrows >> 1;
        const unsigned int* XTu = (const unsigned int*)XTin;
        for (int idx = t; idx < 128 * 64; idx += 256) {
            int f = idx >> 6, np = idx & 63;
            if (np < npair) {
                unsigned int u = XTu[(gx + f) * (AST / 2) + (rows0 >> 1) + np];
                sX[(2 * np) * MSTR + f] = (unsigned short)(u & 0xffffu);
                sX[(2 * np + 1) * MSTR + f] = (unsigned short)(u >> 16);
            }
        }
    }

    int lane = t & 63, mp = t >> 6;
    int quad = lane >> 4, l15 = lane & 15;

    // ---- phase B: preload agg A-frags (wave mp owns features 32mp..32mp+31)
    short8 Afr[2][KSA];
#pragma unroll
    for (int mt = 0; mt < 2; ++mt)
#pragma unroll
        for (int k = 0; k < KSA; ++k)
            Afr[mt][k] = *(const short8*)&XTin[(gx + 32 * mp + 16 * mt + l15) * AST + k * 32 + quad * 8];

    // ---- phase C: agg GEMM, mean -> sM (normal layout)
    for (int nt = ntB; nt < ntE; ++nt) {
        const unsigned short* Ar = Abf + (gn + nt * 16 + l15) * AST;
        floatx4 acc0 = {0.f, 0.f, 0.f, 0.f};
        floatx4 acc1 = {0.f, 0.f, 0.f, 0.f};
#pragma unroll
        for (int k = 0; k < KSA; ++k) {
            short8 Bf = *(const short8*)&Ar[k * 32 + quad * 8];
            acc0 = __builtin_amdgcn_mfma_f32_16x16x32_bf16(Afr[0][k], Bf, acc0, 0, 0, 0);
            acc1 = __builtin_amdgcn_mfma_f32_16x16x32_bf16(Afr[1][k], Bf, acc1, 0, 0, 0);
        }
        int lo = (nt - ntB) * 16 + l15;
        float rl = rliv[gn + nt * 16 + l15];
        unsigned short* mrow = &sM[lo * MSTR + 32 * mp + quad * 4];
        uint2 w0, w1;
        w0.x = pk2(acc0[0] * rl, acc0[1] * rl); w0.y = pk2(acc0[2] * rl, acc0[3] * rl);
        w1.x = pk2(acc1[0] * rl, acc1[1] * rl); w1.y = pk2(acc1[2] * rl, acc1[3] * rl);
        *(uint2*)mrow = w0;
        *(uint2*)(mrow + 16) = w1;
    }
    __syncthreads();

    // ---- phase D: OUT^T = WrT.meanT + WsT.xT + b
    short8 Wr8[2][4], Ws8[2][4];
#pragma unroll
    for (int mt = 0; mt < 2; ++mt) {
        int j = 32 * mp + 16 * mt + l15;
#pragma unroll
        for (int k = 0; k < 4; ++k) {
            Wr8[mt][k] = *(const short8*)&wr_bt[j * HD + k * 32 + quad * 8];
            Ws8[mt][k] = *(const short8*)&ws_bt[j * HD + k * 32 + quad * 8];
        }
    }
    float4 b40 = *(const float4*)&bias[32 * mp + quad * 4];
    float4 b41 = *(const float4*)&bias[32 * mp + 16 + quad * 4];
    float4 pw0, pw1, pv0, pv1;
    if (trg) {
        pw0 = *(const float4*)&pwr[32 * mp + quad * 4];
        pw1 = *(const float4*)&pwr[32 * mp + 16 + quad * 4];
        pv0 = *(const float4*)&pws[32 * mp + quad * 4];
        pv1 = *(const float4*)&pws[32 * mp + 16 + quad * 4];
    }
    float ps0[4] = {0, 0, 0, 0}, ps1[4] = {0, 0, 0, 0};

    for (int nt = ntB; nt < ntE; ++nt) {
        int o = nt * 16 + l15;
        int lo = (nt - ntB) * 16 + l15;
        floatx4 a0 = {b40.x, b40.y, b40.z, b40.w};
        floatx4 a1 = {b41.x, b41.y, b41.z, b41.w};
#pragma unroll
        for (int k = 0; k < 4; ++k) {
            short8 B0 = *(const short8*)&sM[lo * MSTR + k * 32 + quad * 8];
            a0 = __builtin_amdgcn_mfma_f32_16x16x32_bf16(Wr8[0][k], B0, a0, 0, 0, 0);
            a1 = __builtin_amdgcn_mfma_f32_16x16x32_bf16(Wr8[1][k], B0, a1, 0, 0, 0);
        }
#pragma unroll
        for (int k = 0; k < 4; ++k) {
            short8 B1 = *(const short8*)&sX[lo * MSTR + k * 32 + quad * 8];
            a0 = __builtin_amdgcn_mfma_f32_16x16x32_bf16(Ws8[0][k], B1, a0, 0, 0, 0);
            a1 = __builtin_amdgcn_mfma_f32_16x16x32_bf16(Ws8[1][k], B1, a1, 0, 0, 0);
        }
        bool liv = alive[gn + o] != 0.0f;
        float trp = 0.0f, tsp = 0.0f;
#pragma unroll
        for (int rr = 0; rr < 4; ++rr) {
            float v0 = fmaxf(a0[rr], 0.0f);
            float v1 = fmaxf(a1[rr], 0.0f);
            if (liv) { ps0[rr] += v0; ps1[rr] += v1; }
            else { v0 = 0.0f; v1 = 0.0f; }
            if (trg) {
                float w0e = (rr == 0) ? pw0.x : (rr == 1) ? pw0.y : (rr == 2) ? pw0.z : pw0.w;
                float w1e = (rr == 0) ? pw1.x : (rr == 1) ? pw1.y : (rr == 2) ? pw1.z : pw1.w;
                float s0e = (rr == 0) ? pv0.x : (rr == 1) ? pv0.y : (rr == 2) ? pv0.z : pv0.w;
                float s1e = (rr == 0) ? pv1.x : (rr == 1) ? pv1.y : (rr == 2) ? pv1.z : pv1.w;
                trp += v0 * w0e + v1 * w1e;
                tsp += v0 * s0e + v1 * s1e;
            }
            int j0 = 32 * mp + quad * 4 + rr;
            XTout[(gx + j0) * AST + o] = f2b(v0);
            XTout[(gx + j0 + 16) * AST + o] = f2b(v1);
        }
        if (trg) {
            trp += __shfl_xor(trp, 16); trp += __shfl_xor(trp, 32);
            tsp += __shfl_xor(tsp, 16); tsp += __shfl_xor(tsp, 32);
            if (quad == 0) { sTr[mp * 112 + lo] = trp; sTs[mp * 112 + lo] = tsp; }
        }
    }
    // fused readout: reduce over node lanes (l15), atomic into hcat
#pragma unroll
    for (int rr = 0; rr < 4; ++rr) {
        float v = ps0[rr];
        v += __shfl_xor(v, 1); v += __shfl_xor(v, 2); v += __shfl_xor(v, 4); v += __shfl_xor(v, 8);
        float u = ps1[rr];
        u += __shfl_xor(u, 1); u += __shfl_xor(u, 2); u += __shfl_xor(u, 4); u += __shfl_xor(u, 8);
        if (l15 == 0) {
            atomicAdd(&hcat[g * (5 * HD) + layer * HD + 32 * mp + quad * 4 + rr], v);
            atomicAdd(&hcat[g * (5 * HD) + layer * HD + 32 * mp + 16 + quad * 4 + rr], u);
        }
    }
    if (trg) {
        __syncthreads();
        if (t < nrows) {
            trg[gn + rows0 + t] = sTr[t] + sTr[112 + t] + sTr[224 + t] + sTr[336 + t];
            tsg[gn + rows0 + t] = sTs[t] + sTs[112 + t] + sTs[224 + t] + sTs[336 + t];
        }
    }
}

// ---------------- score (parallel): score[d] = (A[d].tr)*rliv + ts + pb  (dead -> -inf)
__global__ __launch_bounds__(256) void k_score(const unsigned short* __restrict__ Abf,
    const float* __restrict__ trb, const float* __restrict__ tsb,
    const float* __restrict__ alive, const float* __restrict__ rliv,
    const float* __restrict__ pb, float* __restrict__ score)
{
    __shared__ float str[AST];
    int b = blockIdx.x;                  // 6400 blocks: 16 rows each
    int g = b / 25, r0 = (b % 25) * 16;
    long gn = (long)g * NPG0;
    int t = threadIdx.x;
    for (int i = t; i < AST; i += 256) str[i] = (i < NPG0) ? trb[gn + i] : 0.0f;
    __syncthreads();
    int lane = t & 63, w = t >> 6;
    float pbv = pb[0];
    for (int rr = 0; rr < 4; ++rr) {
        int row = r0 + w * 4 + rr;
        const unsigned int* Ar = (const unsigned int*)(Abf + (gn + row) * AST);
        float acc = 0.0f;
#pragma unroll
        for (int it = 0; it < 4; ++it) {
            int i = it * 64 + lane;
            if (i < AST / 2) {
                unsigned int a = Ar[i];
                float2 tv = ((const float2*)str)[i];
                acc = fmaf(b2f_lo(a), tv.x, acc);
                acc = fmaf(b2f_hi(a), tv.y, acc);
            }
        }
#pragma unroll
        for (int m2 = 1; m2 < 64; m2 <<= 1) acc += __shfl_xor(acc, m2);
        if (lane == 0) {
            float v = (alive[gn + row] != 0.0f)
                    ? acc * rliv[gn + row] + tsb[gn + row] + pbv : -INFINITY;
            score[gn + row] = v;
        }
    }
}

// ---------------- rliv (parallel): rliv[d] = 1/max(A[d].alive, 1)
__global__ __launch_bounds__(256) void k_rlivk(const unsigned short* __restrict__ Abf,
    const float* __restrict__ alive, float* __restrict__ rliv)
{
    __shared__ float skf[AST];
    int b = blockIdx.x;
    int g = b / 25, r0 = (b % 25) * 16;
    long gn = (long)g * NPG0;
    int t = threadIdx.x;
    for (int i = t; i < AST; i += 256) skf[i] = (i < NPG0) ? alive[gn + i] : 0.0f;
    __syncthreads();
    int lane = t & 63, w = t >> 6;
    for (int rr = 0; rr < 4; ++rr) {
        int row = r0 + w * 4 + rr;
        const unsigned int* Ar = (const unsigned int*)(Abf + (gn + row) * AST);
        float acc = 0.0f;
#pragma unroll
        for (int it = 0; it < 4; ++it) {
            int i = it * 64 + lane;
            if (i < AST / 2) {
                unsigned int a = Ar[i];
                float2 kv = ((const float2*)skf)[i];
                acc = fmaf(b2f_lo(a), kv.x, acc);
                acc = fmaf(b2f_hi(a), kv.y, acc);
            }
        }
#pragma unroll
        for (int m2 = 1; m2 < 64; m2 <<= 1) acc += __shfl_xor(acc, m2);
        if (lane == 0) rliv[gn + row] = 1.0f / fmaxf(acc, 1.0f);
    }
}

// ---------------- per-graph sort: top-K threshold, keep (lowest-index ties), mult, alive
__global__ __launch_bounds__(256) void k_sort(const float* __restrict__ score,
    float* __restrict__ alive, float* __restrict__ multg, int K)
{
    __shared__ float s[512];
    __shared__ float sc[NPG0];
    __shared__ unsigned char keep[NPG0];
    __shared__ int cnt_gt;
    int g = blockIdx.x, t = threadIdx.x;
    long gn = (long)g * NPG0;
    for (int i = t; i < 512; i += 256) {
        float v = (i < NPG0) ? score[gn + i] : -INFINITY;
        s[i] = v;
        if (i < NPG0) sc[i] = v;
    }
    if (t == 0) cnt_gt = 0;
    __syncthreads();
    for (int ksz = 2; ksz <= 512; ksz <<= 1) {
        for (int jsz = ksz >> 1; jsz >= 1; jsz >>= 1) {
            for (int i = t; i < 512; i += 256) {
                int ixj = i ^ jsz;
                if (ixj > i) {
                    float a = s[i], c = s[ixj];
                    bool up = ((i & ksz) == 0);
                    if ((a > c) == up) { s[i] = c; s[ixj] = a; }
                }
            }
            __syncthreads();
        }
    }
    float thr = s[512 - K];
    for (int n = t; n < NPG0; n += 256)
        if (sc[n] > thr) atomicAdd(&cnt_gt, 1);
    __syncthreads();
    if (t == 0) {   // tie-break: lowest index (matches lax.top_k)
        int m = K - cnt_gt, tk = 0;
        for (int n = 0; n < NPG0; n++) {
            bool kp = sc[n] > thr;
            if (!kp && sc[n] == thr && tk < m) { kp = true; tk++; }
            keep[n] = kp ? 1 : 0;
        }
    }
    __syncthreads();
    for (int n = t; n < NPG0; n += 256) {
        bool kp = keep[n] != 0;
        multg[gn + n] = kp ? tanhf(sc[n]) : 0.0f;
        alive[gn + n] = kp ? 1.0f : 0.0f;
    }
}

// ---------------- XT scale (parallel): XT[g][f][n] *= mult[g*NPG0+n]; pads -> 0
__global__ __launch_bounds__(256) void k_scale(unsigned short* __restrict__ XT,
                                               const float* __restrict__ multg) {
    long idx = (long)blockIdx.x * 256 + threadIdx.x;   // u32 units
    int cpair = (int)(idx % (AST / 2));
    int gf = (int)(idx / (AST / 2));
    int g = gf >> 7;
    int n0 = 2 * cpair;
    unsigned int* p = &((unsigned int*)XT)[idx];
    unsigned int u = *p;
    float m0 = (n0 < NPG0) ? multg[(long)g * NPG0 + n0] : 0.0f;
    float m1 = (n0 + 1 < NPG0) ? multg[(long)g * NPG0 + n0 + 1] : 0.0f;
    *p = pk2(b2f_lo(u) * m0, b2f_hi(u) * m1);
}

// ---------------- final MLP + log_softmax (hcat holds SUMS; divide here)
__global__ __launch_bounds__(256) void k_mlp(const float* __restrict__ h, const float* __restrict__ w1,
    const float* __restrict__ b1, const float* __restrict__ w2,
    const float* __restrict__ b2, float* __restrict__ out) {
    __shared__ float shg[5 * HD];
    __shared__ float prt[256];
    __shared__ float h1[HD];
    __shared__ float red[HD];
    __shared__ float lg[2];
    const float inv[5] = {1.0f/400.0f, 1.0f/400.0f, 1.0f/320.0f, 1.0f/320.0f, 1.0f/256.0f};
    int g = blockIdx.x, t = threadIdx.x;
    for (int k = t; k < 5 * HD; k += 256) shg[k] = h[g * (5 * HD) + k] * inv[k >> 7];
    __syncthreads();
    int j = t & 127, half = t >> 7;
    float acc = half ? 0.0f : b1[j];
    for (int k = half * 320; k < half * 320 + 320; ++k)
        acc = fmaf(shg[k], w1[k * HD + j], acc);
    prt[t] = acc;
    __syncthreads();
    if (t < HD) h1[t] = fmaxf(prt[t] + prt[t + 128], 0.0f);
    __syncthreads();
    for (int c = 0; c < 2; c++) {
        if (t < HD) red[t] = h1[t] * w2[t * 2 + c];
        __syncthreads();
        for (int st = 64; st > 0; st >>= 1) {
            if (t < st) red[t] += red[t + st];
            __syncthreads();
        }
        if (t == 0) lg[c] = red[0] + b2[c];
        __syncthreads();
    }
    if (t == 0) {
        float l0 = lg[0], l1 = lg[1];
        float m = fmaxf(l0, l1);
        float lse = m + logf(expf(l0 - m) + expf(l1 - m));
        out[g * 2 + 0] = l0 - lse;
        out[g * 2 + 1] = l1 - lse;
    }
}

extern "C" void kernel_launch(void* const* d_in, const int* in_sizes, int n_in,
                              void* d_out, int out_size, void* d_ws, size_t ws_size,
                              hipStream_t stream) {
    const float* x_in   = (const float*)d_in[0];
    const int*   eidx   = (const int*)d_in[1];
    const int*   e_src  = eidx;
    const int*   e_dst  = eidx + NE;
    const float* c1_wr  = (const float*)d_in[3];
    const float* c1_ws  = (const float*)d_in[4];
    const float* c1_b   = (const float*)d_in[5];
    const float* cs_wr  = (const float*)d_in[6];
    const float* cs_ws  = (const float*)d_in[7];
    const float* cs_b   = (const float*)d_in[8];
    const float* p_wr   = (const float*)d_in[9];
    const float* p_ws   = (const float*)d_in[10];
    const float* p_b    = (const float*)d_in[11];
    const float* l1_w   = (const float*)d_in[12];
    const float* l1_b   = (const float*)d_in[13];
    const float* l2_w   = (const float*)d_in[14];
    const float* l2_b   = (const float*)d_in[15];
    float* out = (float*)d_out;

    char* ws = (char*)d_ws;
    size_t off = 0;
    float* alive = (float*)(ws + off);                 off += (size_t)NN * 4;
    float* rliv  = (float*)(ws + off);                 off += (size_t)NN * 4;
    float* hcat  = (float*)(ws + off);                 off += (size_t)BGR * 5 * HD * 4;
    unsigned short* wbt = (unsigned short*)(ws + off); off += (size_t)10 * HD * HD * 2;
    unsigned short* Abf = (unsigned short*)(ws + off); off += (size_t)NN * AST * 2;
    unsigned short* XT0 = (unsigned short*)(ws + off); off += (size_t)BGR * HD * AST * 2;
    unsigned short* XT1 = (unsigned short*)(ws + off); off += (size_t)BGR * HD * AST * 2;
    float* trb   = (float*)(ws + off);                 off += (size_t)NN * 4;
    float* tsb   = (float*)(ws + off);                 off += (size_t)NN * 4;
    float* scoreb = (float*)(ws + off);                off += (size_t)NN * 4;
    float* multb = (float*)(ws + off);                 off += (size_t)NN * 4;
    unsigned char* A8 = (unsigned char*)XT0;           // dead after k_acvt; xpose overwrites

    hipMemsetAsync(A8, 0, (size_t)NN * AST, stream);
    hipMemsetAsync(hcat, 0, (size_t)BGR * 5 * HD * 4, stream);
    k_abuild<<<NE / 256, 256, 0, stream>>>(e_src, e_dst, (unsigned int*)A8);
    k_acvt<<<NN / 4, 256, 0, stream>>>(A8, Abf, alive, rliv);
    k_wcvt<<<dim3(64, 10), 256, 0, stream>>>(c1_wr, c1_ws, cs_wr, cs_ws, wbt);
    k_xpose<<<BGR * 4, 256, 0, stream>>>(x_in, XT0);

    unsigned short* bt_wr[5] = { wbt + 0 * HD * HD, wbt + 2 * HD * HD, wbt + 3 * HD * HD, wbt + 4 * HD * HD, wbt + 5 * HD * HD };
    unsigned short* bt_ws[5] = { wbt + 1 * HD * HD, wbt + 6 * HD * HD, wbt + 7 * HD * HD, wbt + 8 * HD * HD, wbt + 9 * HD * HD };

    // conv1: XT0 -> XT1
    k_layer4<<<BGR * 4, 256, 0, stream>>>(XT0, XT1, Abf, alive, rliv,
        bt_wr[0], bt_ws[0], c1_b, hcat, 0, nullptr, nullptr, nullptr, nullptr);
    // convs[0]: XT1 -> XT0 (+ pool-0 dots)
    k_layer4<<<BGR * 4, 256, 0, stream>>>(XT1, XT0, Abf, alive, rliv,
        bt_wr[1], bt_ws[1], cs_b + 0 * HD, hcat, 1, p_wr + 0 * HD, p_ws + 0 * HD, trb, tsb);
    // pool 0 (K=320)
    k_score<<<BGR * 25, 256, 0, stream>>>(Abf, trb, tsb, alive, rliv, p_b + 0, scoreb);
    k_sort<<<BGR, 256, 0, stream>>>(scoreb, alive, multb, 320);
    k_rlivk<<<BGR * 25, 256, 0, stream>>>(Abf, alive, rliv);
    k_scale<<<(int)(((long)BGR * HD * (AST / 2)) / 256), 256, 0, stream>>>(XT0, multb);
    // convs[1]: XT0 -> XT1
    k_layer4<<<BGR * 4, 256, 0, stream>>>(XT0, XT1, Abf, alive, rliv,
        bt_wr[2], bt_ws[2], cs_b + 1 * HD, hcat, 2, nullptr, nullptr, nullptr, nullptr);
    // convs[2]: XT1 -> XT0 (+ pool-1 dots)
    k_layer4<<<BGR * 4, 256, 0, stream>>>(XT1, XT0, Abf, alive, rliv,
        bt_wr[3], bt_ws[3], cs_b + 2 * HD, hcat, 3, p_wr + 1 * HD, p_ws + 1 * HD, trb, tsb);
    // pool 1 (K=256)
    k_score<<<BGR * 25, 256, 0, stream>>>(Abf, trb, tsb, alive, rliv, p_b + 1, scoreb);
    k_sort<<<BGR, 256, 0, stream>>>(scoreb, alive, multb, 256);
    k_rlivk<<<BGR * 25, 256, 0, stream>>>(Abf, alive, rliv);
    k_scale<<<(int)(((long)BGR * HD * (AST / 2)) / 256), 256, 0, stream>>>(XT0, multb);
    // convs[3]: XT0 -> XT1
    k_layer4<<<BGR * 4, 256, 0, stream>>>(XT0, XT1, Abf, alive, rliv,
        bt_wr[4], bt_ws[4], cs_b + 3 * HD, hcat, 4, nullptr, nullptr, nullptr, nullptr);
    // MLP head
    k_mlp<<<BGR, 256, 0, stream>>>(hcat, l1_w, l1_b, l2_w, l2_b, out);
}